// Round 8
// baseline (286.589 us; speedup 1.0000x reference)
//
#include <hip/hip_runtime.h>
#include <stdint.h>

typedef __bf16 bf16_t;
typedef __bf16 bf16x8 __attribute__((ext_vector_type(8)));
typedef __bf16 bf16x4 __attribute__((ext_vector_type(4)));
typedef float floatx4 __attribute__((ext_vector_type(4)));

#define AS3(p) ((__attribute__((address_space(3))) void*)(p))
#define AS1(p) ((__attribute__((address_space(1))) void*)(void*)(p))

// ---------- fused prep: cvt x (f32->bf16) + transpose-convert wq/wk/wv/wo ----------
__global__ __launch_bounds__(256) void prep_k(const float* __restrict__ x,
                                              const float* __restrict__ wq,
                                              const float* __restrict__ wk,
                                              const float* __restrict__ wv,
                                              const float* __restrict__ wo,
                                              bf16_t* __restrict__ xb,
                                              bf16_t* __restrict__ wt) {
  __shared__ __align__(16) bf16_t T[64][68];
  const int b = blockIdx.x;
  const int t = threadIdx.x;
  if (b < 2048) {
    const int i = (b * 256 + t) * 8;
    floatx4 a = *(const floatx4*)&x[i];
    floatx4 c = *(const floatx4*)&x[i + 4];
    bf16x8 o;
#pragma unroll
    for (int j = 0; j < 4; ++j) { o[j] = (bf16_t)a[j]; o[4 + j] = (bf16_t)c[j]; }
    *(bf16x8*)&xb[i] = o;
    return;
  }
  int b2 = b - 2048;
  const float* src;
  int ncols, bx, by;
  bf16_t* dst;
  if (b2 < 1024) {
    src = wq; ncols = 2048; dst = wt; bx = b2 & 31; by = b2 >> 5;
  } else if (b2 < 1280) {
    const int i2 = b2 - 1024;
    src = wk; ncols = 512; dst = wt + (size_t)2048 * 2048; bx = i2 & 7; by = i2 >> 3;
  } else if (b2 < 1536) {
    const int i2 = b2 - 1280;
    src = wv; ncols = 512; dst = wt + (size_t)2560 * 2048; bx = i2 & 7; by = i2 >> 3;
  } else {
    const int i2 = b2 - 1536;
    src = wo; ncols = 2048; dst = wt + (size_t)3072 * 2048; bx = i2 & 31; by = i2 >> 5;
  }
  const int nt = bx * 64, kt = by * 64;
  const int r0 = t >> 4;         // 0..15
  const int c0 = (t & 15) << 2;  // 0..60
#pragma unroll
  for (int p = 0; p < 4; ++p) {
    const int row = p * 16 + r0;
    floatx4 v = *(const floatx4*)&src[(size_t)(kt + row) * ncols + nt + c0];
    bf16x4 bb;
#pragma unroll
    for (int i = 0; i < 4; ++i) bb[i] = (bf16_t)v[i];
    *(bf16x4*)&T[row][c0] = bb;
  }
  __syncthreads();
#pragma unroll
  for (int p = 0; p < 4; ++p) {
    const int n = p * 16 + r0;
    bf16x4 tmp;
#pragma unroll
    for (int i = 0; i < 4; ++i) tmp[i] = T[c0 + i][n];
    *(bf16x4*)&dst[(size_t)(nt + n) * 2048 + kt + c0] = tmp;
  }
}

// ---------- GEMM: C[m][n] = sum_k A[m][k] * Bt[n][k], K=2048, A/Bt bf16 ----------
// R8: exact R0 structure (fastest measured: 42.9us, single-buffered, BK=64,
// plain __syncthreads, 4 waves, acc[4][2], zero bank conflicts) + the one
// validated add-on: XCD-rectangle swizzle (FETCH 41->33.5MB, time-neutral).
// Five schedule variants (dbuf/BK128/counted-vmcnt/B-reg) all failed to beat
// R0 -> gemm surgery stopped; this is the keep.
template <int EPI>
__global__ __launch_bounds__(256) void gemm_k(const bf16_t* __restrict__ A,
                                              const bf16_t* __restrict__ Bt,
                                              bf16_t* __restrict__ o0,
                                              bf16_t* __restrict__ o1,
                                              bf16_t* __restrict__ o2,
                                              float* __restrict__ fo,
                                              const float* __restrict__ fcos,
                                              const float* __restrict__ fsin) {
  constexpr int K = 2048;
  __shared__ __align__(16) bf16_t As[64 * 64];
  __shared__ __align__(16) bf16_t Bs[128 * 64];
  const int tid = threadIdx.x;
  const int lane = tid & 63;
  const int w = tid >> 6;
  const int quad = lane >> 4;
  const int l15 = lane & 15;

  // XCD-rectangle swizzle: nwg % 8 == 0; 8 XCDs tiled 2(x) x 4(y).
  const int nx = gridDim.x, ny = gridDim.y;
  const int flat = blockIdx.y * nx + blockIdx.x;
  const int xcd = flat & 7;
  const int c = flat >> 3;  // within-XCD order
  const int CW = nx >> 1, CH = ny >> 2;
  const int bx = (xcd & 1) * CW + (c % CW);
  const int by = (xcd >> 1) * CH + (c / CW);
  const int m0 = by * 64;
  const int n0 = bx * 128;

  // staging: lane covers row (base + lane>>3), swizzled chunk (lane&7)^(row&7)
  const int sr = lane >> 3;
  const int sc = ((lane & 7) ^ (sr & 7)) << 3;
  const bf16_t* gA = A + (size_t)(m0 + w * 16 + sr) * K + sc;   // A instrs j=2w,2w+1
  const bf16_t* gB = Bt + (size_t)(n0 + w * 32 + sr) * K + sc;  // B instrs j=4w..4w+3
  bf16_t* lA = &As[w * 1024];
  bf16_t* lB = &Bs[w * 2048];
  floatx4 acc[4][2] = {};

  for (int k0 = 0; k0 < K; k0 += 64) {
    __builtin_amdgcn_global_load_lds(AS1(gA + k0), AS3(lA), 16, 0, 0);
    __builtin_amdgcn_global_load_lds(AS1(gA + 8 * K + k0), AS3(lA + 512), 16, 0, 0);
#pragma unroll
    for (int qq = 0; qq < 4; ++qq)
      __builtin_amdgcn_global_load_lds(AS1(gB + (size_t)qq * 8 * K + k0),
                                       AS3(lB + qq * 512), 16, 0, 0);
    __syncthreads();
#pragma unroll
    for (int kk = 0; kk < 2; ++kk) {
      const int co = ((kk * 4 + quad) ^ (l15 & 7)) << 3;  // per-lane const offset
      bf16x8 af[4], bfr[2];
#pragma unroll
      for (int i = 0; i < 4; ++i) af[i] = *(const bf16x8*)&As[(i * 16 + l15) * 64 + co];
#pragma unroll
      for (int i = 0; i < 2; ++i)
        bfr[i] = *(const bf16x8*)&Bs[(w * 32 + i * 16 + l15) * 64 + co];
#pragma unroll
      for (int mi = 0; mi < 4; ++mi)
#pragma unroll
        for (int ni = 0; ni < 2; ++ni)
          acc[mi][ni] =
              __builtin_amdgcn_mfma_f32_16x16x32_bf16(af[mi], bfr[ni], acc[mi][ni], 0, 0, 0);
    }
    __syncthreads();
  }

  if constexpr (EPI == 0) {
#pragma unroll
    for (int ni = 0; ni < 2; ++ni) {
      const int col = n0 + w * 32 + ni * 16 + l15;
#pragma unroll
      for (int mi = 0; mi < 4; ++mi) {
        const int sb = m0 + mi * 16 + quad * 4;
        if (col < 2560) {  // uniform per wave (boundaries are multiples of 16)
          const int fi = (col & 63) >> 1;
#pragma unroll
          for (int r = 0; r < 4; ++r) {
            const float v = acc[mi][ni][r];
            const float prt = __shfl_xor(v, 1);  // partner column within rope pair
            const int s = sb + r;
            const float cc = fcos[s * 32 + fi];
            const float sn = fsin[s * 32 + fi];
            const float ov = (col & 1) ? (prt * sn + v * cc) : (v * cc - prt * sn);
            if (col < 2048)
              o0[(size_t)s * 2048 + col] = (bf16_t)ov;
            else
              o1[(size_t)s * 512 + (col - 2048)] = (bf16_t)ov;
          }
        } else {
          // sigma permutation within the 32-aligned s-block:
          // logical (t=mi&1, qs=quad, r) -> storage quad*8 + (mi&1)*4 + r
          const int sp = (sb & ~31) | (quad * 8 + (mi & 1) * 4);
          bf16x4 pv;
#pragma unroll
          for (int r = 0; r < 4; ++r) pv[r] = (bf16_t)acc[mi][ni][r];
          *(bf16x4*)&o2[(size_t)(col - 2560) * 2048 + sp] = pv;
        }
      }
    }
  } else {
#pragma unroll
    for (int ni = 0; ni < 2; ++ni) {
      const int col = n0 + w * 32 + ni * 16 + l15;
#pragma unroll
      for (int mi = 0; mi < 4; ++mi) {
        const int sb = m0 + mi * 16 + quad * 4;
#pragma unroll
        for (int r = 0; r < 4; ++r) fo[(size_t)(sb + r) * 2048 + col] = acc[mi][ni][r];
      }
    }
  }
}

// ---------- flash attention, S^T formulation; R8: DE-STAGED (no LDS, no barriers) ----------
// K/V per head-group is 2x256KB shared by 128 blocks -> L2/L3-resident.
// LDS staging cost per 32-kv tile (8KB gload_lds + 32KB ds_read + 2 barriers
// locking 4 waves in lockstep) was pure overhead (Common-mistake #7 / m169).
// Fragments now load straight from global with the identical per-lane layout
// the staged path produced:
//   kX: K[kb + (X>>1)*16 + l15][g*64 + (X&1)*32 + quad*8 ..+7]
//   vX: V^T[g*64 + X*16 + l15][kb + quad*8 ..+7]
// Each wave iterates only its own masked window (no idle iterations).
__global__ __launch_bounds__(256) void attn_k(const bf16_t* __restrict__ qb_,
                                              const bf16_t* __restrict__ kb_,
                                              const bf16_t* __restrict__ vt_,
                                              bf16_t* __restrict__ ob_) {
  const int lane = threadIdx.x & 63, w = threadIdx.x >> 6;
  const int quad = lane >> 4, l15 = lane & 15;
  const int h = blockIdx.y, g = h >> 2;
  const int qb = (gridDim.x - 1 - blockIdx.x) * 64;  // heavy blocks first
  const int qw = qb + w * 16;
  const int q = qw + l15;
  const bf16_t* qrow = qb_ + (size_t)q * 2048 + h * 64;
  const bf16x8 qf0 = *(const bf16x8*)(qrow + quad * 8);
  const bf16x8 qf1 = *(const bf16x8*)(qrow + 32 + quad * 8);
  floatx4 acc0 = {}, acc1 = {}, acc2 = {}, acc3 = {}, accl = {};
  const float SC = 0.125f * 1.44269504088896340736f;  // scale * log2(e)
  bf16x8 ones;
#pragma unroll
  for (int i = 0; i < 8; ++i) ones[i] = (bf16_t)1.0f;

  int myS = qw - 1024;
  if (myS < 0) myS = 0;
  myS &= ~31;
  const int myE = qw + 16;

  const bf16_t* gk = kb_ + (size_t)l15 * 512 + g * 64 + quad * 8;
  const bf16_t* gv = vt_ + (size_t)(g * 64 + l15) * 2048 + quad * 8;

#define MSK(pv, key)                                        \
  do {                                                      \
    if ((key) > q || (key) + 1024 < q) pv = -1.0e30f;       \
  } while (0)

  for (int kb = myS; kb < myE; kb += 32) {
    const bf16_t* kbase = gk + (size_t)kb * 512;
    const bf16x8 k0 = *(const bf16x8*)(kbase);
    const bf16x8 k1 = *(const bf16x8*)(kbase + 32);
    const bf16x8 k2 = *(const bf16x8*)(kbase + 16 * 512);
    const bf16x8 k3 = *(const bf16x8*)(kbase + 16 * 512 + 32);
    const bf16_t* vbase = gv + kb;
    const bf16x8 v0 = *(const bf16x8*)(vbase);
    const bf16x8 v1 = *(const bf16x8*)(vbase + 16 * 2048);
    const bf16x8 v2 = *(const bf16x8*)(vbase + 32 * 2048);
    const bf16x8 v3 = *(const bf16x8*)(vbase + 48 * 2048);
    floatx4 z0 = {}, z1 = {};
    z0 = __builtin_amdgcn_mfma_f32_16x16x32_bf16(k0, qf0, z0, 0, 0, 0);
    z0 = __builtin_amdgcn_mfma_f32_16x16x32_bf16(k1, qf1, z0, 0, 0, 0);
    z1 = __builtin_amdgcn_mfma_f32_16x16x32_bf16(k2, qf0, z1, 0, 0, 0);
    z1 = __builtin_amdgcn_mfma_f32_16x16x32_bf16(k3, qf1, z1, 0, 0, 0);
    float p0 = z0[0] * SC - 32.0f, p1 = z0[1] * SC - 32.0f;
    float p2 = z0[2] * SC - 32.0f, p3 = z0[3] * SC - 32.0f;
    float p4 = z1[0] * SC - 32.0f, p5 = z1[1] * SC - 32.0f;
    float p6 = z1[2] * SC - 32.0f, p7 = z1[3] * SC - 32.0f;
    if ((kb + 31 > qw) || (kb < qw - 1009)) {  // wave-uniform edge mask
      const int kq = kb + quad * 4;
      MSK(p0, kq + 0); MSK(p1, kq + 1); MSK(p2, kq + 2); MSK(p3, kq + 3);
      MSK(p4, kq + 16); MSK(p5, kq + 17); MSK(p6, kq + 18); MSK(p7, kq + 19);
    }
    bf16x8 pf;  // == P^T B-fragment directly (sigma-permuted V columns)
    pf[0] = (bf16_t)__builtin_amdgcn_exp2f(p0);
    pf[1] = (bf16_t)__builtin_amdgcn_exp2f(p1);
    pf[2] = (bf16_t)__builtin_amdgcn_exp2f(p2);
    pf[3] = (bf16_t)__builtin_amdgcn_exp2f(p3);
    pf[4] = (bf16_t)__builtin_amdgcn_exp2f(p4);
    pf[5] = (bf16_t)__builtin_amdgcn_exp2f(p5);
    pf[6] = (bf16_t)__builtin_amdgcn_exp2f(p6);
    pf[7] = (bf16_t)__builtin_amdgcn_exp2f(p7);
    accl = __builtin_amdgcn_mfma_f32_16x16x32_bf16(ones, pf, accl, 0, 0, 0);
    acc0 = __builtin_amdgcn_mfma_f32_16x16x32_bf16(v0, pf, acc0, 0, 0, 0);
    acc1 = __builtin_amdgcn_mfma_f32_16x16x32_bf16(v1, pf, acc1, 0, 0, 0);
    acc2 = __builtin_amdgcn_mfma_f32_16x16x32_bf16(v2, pf, acc2, 0, 0, 0);
    acc3 = __builtin_amdgcn_mfma_f32_16x16x32_bf16(v3, pf, acc3, 0, 0, 0);
  }
#undef MSK

  const float inv = 1.0f / accl[0];
  bf16_t* obase = ob_ + (size_t)q * 2048 + h * 64 + quad * 4;
  bf16x4 ov;
#pragma unroll
  for (int r = 0; r < 4; ++r) ov[r] = (bf16_t)(acc0[r] * inv);
  *(bf16x4*)(obase) = ov;
#pragma unroll
  for (int r = 0; r < 4; ++r) ov[r] = (bf16_t)(acc1[r] * inv);
  *(bf16x4*)(obase + 16) = ov;
#pragma unroll
  for (int r = 0; r < 4; ++r) ov[r] = (bf16_t)(acc2[r] * inv);
  *(bf16x4*)(obase + 32) = ov;
#pragma unroll
  for (int r = 0; r < 4; ++r) ov[r] = (bf16_t)(acc3[r] * inv);
  *(bf16x4*)(obase + 48) = ov;
}

extern "C" void kernel_launch(void* const* d_in, const int* in_sizes, int n_in, void* d_out,
                              int out_size, void* d_ws, size_t ws_size, hipStream_t stream) {
  (void)in_sizes;
  (void)n_in;
  (void)out_size;
  (void)ws_size;
  const float* x = (const float*)d_in[0];
  const float* wq = (const float*)d_in[1];
  const float* wk = (const float*)d_in[2];
  const float* wv = (const float*)d_in[3];
  const float* wo = (const float*)d_in[4];
  const float* fcos = (const float*)d_in[5];
  const float* fsin = (const float*)d_in[6];
  float* out = (float*)d_out;

  bf16_t* xb = (bf16_t*)d_ws;
  bf16_t* wt = xb + (size_t)2048 * 2048;
  bf16_t* qbuf = wt + (size_t)5120 * 2048;
  bf16_t* kbuf = qbuf + (size_t)2048 * 2048;
  bf16_t* vtb = kbuf + (size_t)2048 * 512;
  bf16_t* att = vtb + (size_t)512 * 2048;

  prep_k<<<4608, 256, 0, stream>>>(x, wq, wk, wv, wo, xb, wt);
  gemm_k<0><<<dim3(24, 32), 256, 0, stream>>>(xb, wt, qbuf, kbuf, vtb, nullptr, fcos, fsin);
  attn_k<<<dim3(32, 32), 256, 0, stream>>>(qbuf, kbuf, vtb, att);
  gemm_k<1><<<dim3(16, 32), 256, 0, stream>>>(att, wt + (size_t)3072 * 2048, nullptr, nullptr,
                                              nullptr, out, fcos, fsin);
}

// Round 9
// 222.478 us; speedup vs baseline: 1.2882x; 1.2882x over previous
//
#include <hip/hip_runtime.h>
#include <stdint.h>

typedef __bf16 bf16_t;
typedef __bf16 bf16x8 __attribute__((ext_vector_type(8)));
typedef __bf16 bf16x4 __attribute__((ext_vector_type(4)));
typedef float floatx4 __attribute__((ext_vector_type(4)));

#define AS3(p) ((__attribute__((address_space(3))) void*)(p))
#define AS1(p) ((__attribute__((address_space(1))) void*)(void*)(p))

// ---------- fused prep: cvt x (f32->bf16) + transpose-convert wq/wk/wv/wo ----------
__global__ __launch_bounds__(256) void prep_k(const float* __restrict__ x,
                                              const float* __restrict__ wq,
                                              const float* __restrict__ wk,
                                              const float* __restrict__ wv,
                                              const float* __restrict__ wo,
                                              bf16_t* __restrict__ xb,
                                              bf16_t* __restrict__ wt) {
  __shared__ __align__(16) bf16_t T[64][68];
  const int b = blockIdx.x;
  const int t = threadIdx.x;
  if (b < 2048) {
    const int i = (b * 256 + t) * 8;
    floatx4 a = *(const floatx4*)&x[i];
    floatx4 c = *(const floatx4*)&x[i + 4];
    bf16x8 o;
#pragma unroll
    for (int j = 0; j < 4; ++j) { o[j] = (bf16_t)a[j]; o[4 + j] = (bf16_t)c[j]; }
    *(bf16x8*)&xb[i] = o;
    return;
  }
  int b2 = b - 2048;
  const float* src;
  int ncols, bx, by;
  bf16_t* dst;
  if (b2 < 1024) {
    src = wq; ncols = 2048; dst = wt; bx = b2 & 31; by = b2 >> 5;
  } else if (b2 < 1280) {
    const int i2 = b2 - 1024;
    src = wk; ncols = 512; dst = wt + (size_t)2048 * 2048; bx = i2 & 7; by = i2 >> 3;
  } else if (b2 < 1536) {
    const int i2 = b2 - 1280;
    src = wv; ncols = 512; dst = wt + (size_t)2560 * 2048; bx = i2 & 7; by = i2 >> 3;
  } else {
    const int i2 = b2 - 1536;
    src = wo; ncols = 2048; dst = wt + (size_t)3072 * 2048; bx = i2 & 31; by = i2 >> 5;
  }
  const int nt = bx * 64, kt = by * 64;
  const int r0 = t >> 4;         // 0..15
  const int c0 = (t & 15) << 2;  // 0..60
#pragma unroll
  for (int p = 0; p < 4; ++p) {
    const int row = p * 16 + r0;
    floatx4 v = *(const floatx4*)&src[(size_t)(kt + row) * ncols + nt + c0];
    bf16x4 bb;
#pragma unroll
    for (int i = 0; i < 4; ++i) bb[i] = (bf16_t)v[i];
    *(bf16x4*)&T[row][c0] = bb;
  }
  __syncthreads();
#pragma unroll
  for (int p = 0; p < 4; ++p) {
    const int n = p * 16 + r0;
    bf16x4 tmp;
#pragma unroll
    for (int i = 0; i < 4; ++i) tmp[i] = T[c0 + i][n];
    *(bf16x4*)&dst[(size_t)(nt + n) * 2048 + kt + c0] = tmp;
  }
}

// ---------- GEMM: C[m][n] = sum_k A[m][k] * Bt[n][k], K=2048, A/Bt bf16 ----------
// R9: tile 32(M) x 128(N), TWO waves, wave tile 32x64 (acc[2][4]).
// Same 12 waves/CU as R0 (gemm0: 6 blocks/CU x 2 waves) but barrier domain
// shrinks 4 waves -> 2: a vmcnt(0) drain now stalls 1/6 of the CU instead of
// 1/3, so cross-block overlap (the only working latency cover; R1/R5/R6
// schedule levers all null) is 2x finer-grained. R2's failure was TLP loss
// (6 waves/CU), not the 2-wave block per se. LDS 4KB A + 16KB B = 20KB,
// single-buffered, BK=64, plain __syncthreads (R0 schedule, proven best).
// XCD-rectangle swizzle kept (FETCH -20%, validated). Zero-conflict
// chunk-swizzle (slot c^(r&7)) via permuted global source chunk per lane.
template <int EPI>
__global__ __launch_bounds__(128) void gemm_k(const bf16_t* __restrict__ A,
                                              const bf16_t* __restrict__ Bt,
                                              bf16_t* __restrict__ o0,
                                              bf16_t* __restrict__ o1,
                                              bf16_t* __restrict__ o2,
                                              float* __restrict__ fo,
                                              const float* __restrict__ fcos,
                                              const float* __restrict__ fsin) {
  constexpr int K = 2048;
  __shared__ __align__(16) bf16_t As[32 * 64];
  __shared__ __align__(16) bf16_t Bs[128 * 64];
  const int tid = threadIdx.x;
  const int lane = tid & 63;
  const int w = tid >> 6;  // 0..1
  const int quad = lane >> 4;
  const int l15 = lane & 15;

  // XCD-rectangle swizzle: nwg % 8 == 0; 8 XCDs tiled 2(x) x 4(y).
  const int nx = gridDim.x, ny = gridDim.y;
  const int flat = blockIdx.y * nx + blockIdx.x;
  const int xcd = flat & 7;
  const int c = flat >> 3;  // within-XCD order
  const int CW = nx >> 1, CH = ny >> 2;
  const int bx = (xcd & 1) * CW + (c % CW);
  const int by = (xcd >> 1) * CH + (c / CW);
  const int m0 = by * 32;
  const int n0 = bx * 128;

  // staging: lane covers row (base + lane>>3), swizzled chunk (lane&7)^(row&7)
  const int sr = lane >> 3;
  const int sc = ((lane & 7) ^ (sr & 7)) << 3;
  const bf16_t* gA = A + (size_t)(m0 + w * 16 + sr) * K + sc;   // 2 instrs/wave
  const bf16_t* gB = Bt + (size_t)(n0 + w * 64 + sr) * K + sc;  // 8 instrs/wave
  bf16_t* lA = &As[w * 1024];
  bf16_t* lB = &Bs[w * 4096];
  floatx4 acc[2][4] = {};

  for (int k0 = 0; k0 < K; k0 += 64) {
    __builtin_amdgcn_global_load_lds(AS1(gA + k0), AS3(lA), 16, 0, 0);
    __builtin_amdgcn_global_load_lds(AS1(gA + 8 * K + k0), AS3(lA + 512), 16, 0, 0);
#pragma unroll
    for (int j = 0; j < 8; ++j)
      __builtin_amdgcn_global_load_lds(AS1(gB + (size_t)j * 8 * K + k0),
                                       AS3(lB + j * 512), 16, 0, 0);
    __syncthreads();
#pragma unroll
    for (int kk = 0; kk < 2; ++kk) {
      const int co = ((kk * 4 + quad) ^ (l15 & 7)) << 3;  // per-lane const offset
      bf16x8 af[2], bfr[4];
#pragma unroll
      for (int i = 0; i < 2; ++i) af[i] = *(const bf16x8*)&As[(i * 16 + l15) * 64 + co];
#pragma unroll
      for (int i = 0; i < 4; ++i)
        bfr[i] = *(const bf16x8*)&Bs[(w * 64 + i * 16 + l15) * 64 + co];
#pragma unroll
      for (int mi = 0; mi < 2; ++mi)
#pragma unroll
        for (int ni = 0; ni < 4; ++ni)
          acc[mi][ni] =
              __builtin_amdgcn_mfma_f32_16x16x32_bf16(af[mi], bfr[ni], acc[mi][ni], 0, 0, 0);
    }
    __syncthreads();
  }

  if constexpr (EPI == 0) {
#pragma unroll
    for (int ni = 0; ni < 4; ++ni) {
      const int col = n0 + w * 64 + ni * 16 + l15;
#pragma unroll
      for (int mi = 0; mi < 2; ++mi) {
        const int sb = m0 + mi * 16 + quad * 4;
        if (col < 2560) {  // uniform per wave (boundaries are multiples of 16)
          const int fi = (col & 63) >> 1;
#pragma unroll
          for (int r = 0; r < 4; ++r) {
            const float v = acc[mi][ni][r];
            const float prt = __shfl_xor(v, 1);  // partner column within rope pair
            const int s = sb + r;
            const float cc = fcos[s * 32 + fi];
            const float sn = fsin[s * 32 + fi];
            const float ov = (col & 1) ? (prt * sn + v * cc) : (v * cc - prt * sn);
            if (col < 2048)
              o0[(size_t)s * 2048 + col] = (bf16_t)ov;
            else
              o1[(size_t)s * 512 + (col - 2048)] = (bf16_t)ov;
          }
        } else {
          // sigma permutation within the 32-aligned s-block (m0 is 32-aligned,
          // mi in {0,1} spans exactly it): storage quad*8 + mi*4 + r
          const int sp = m0 | (quad * 8 + mi * 4);
          bf16x4 pv;
#pragma unroll
          for (int r = 0; r < 4; ++r) pv[r] = (bf16_t)acc[mi][ni][r];
          *(bf16x4*)&o2[(size_t)(col - 2560) * 2048 + sp] = pv;
        }
      }
    }
  } else {
#pragma unroll
    for (int ni = 0; ni < 4; ++ni) {
      const int col = n0 + w * 64 + ni * 16 + l15;
#pragma unroll
      for (int mi = 0; mi < 2; ++mi) {
        const int sb = m0 + mi * 16 + quad * 4;
#pragma unroll
        for (int r = 0; r < 4; ++r) fo[(size_t)(sb + r) * 2048 + col] = acc[mi][ni][r];
      }
    }
  }
}

// ---------- flash attention, S^T formulation, LDS-staged K/V (R0 restored) ----------
// R8's de-staging regressed 3x: staging shares each K/V tile across 4 waves
// AND gives async one-tile-ahead prefetch. Keep the R0 structure verbatim.
__global__ __launch_bounds__(256) void attn_k(const bf16_t* __restrict__ qb_,
                                              const bf16_t* __restrict__ kb_,
                                              const bf16_t* __restrict__ vt_,
                                              bf16_t* __restrict__ ob_) {
  __shared__ __align__(16) bf16_t sm[2][8 * 512];
  const int lane = threadIdx.x & 63, w = threadIdx.x >> 6;
  const int quad = lane >> 4, l15 = lane & 15;
  const int h = blockIdx.y, g = h >> 2;
  const int qb = (gridDim.x - 1 - blockIdx.x) * 64;  // heavy blocks first
  const int qw = qb + w * 16;
  const int q = qw + l15;
  const bf16_t* qrow = qb_ + (size_t)q * 2048 + h * 64;
  const bf16x8 qf0 = *(const bf16x8*)(qrow + quad * 8);
  const bf16x8 qf1 = *(const bf16x8*)(qrow + 32 + quad * 8);
  floatx4 acc0 = {}, acc1 = {}, acc2 = {}, acc3 = {}, accl = {};
  const float SC = 0.125f * 1.44269504088896340736f;  // scale * log2(e)
  bf16x8 ones;
#pragma unroll
  for (int i = 0; i < 8; ++i) ones[i] = (bf16_t)1.0f;

  int kbB = qb - 1024;
  if (kbB < 0) kbB = 0;
  kbB &= ~31;
  const int nT = (qb + 64 - kbB) >> 5;  // block-level tile count
  int myS = qw - 1024;
  if (myS < 0) myS = 0;
  myS &= ~31;
  const int myE = qw + 16;

  const int lr = lane & 15, lc = lane >> 4;
  const bf16_t* gk = kb_ + (size_t)(kbB + (w >> 1) * 16 + lr) * 512 + g * 64 +
                     ((w & 1) * 4 + lc) * 8;
  const bf16_t* gv = vt_ + (size_t)(g * 64 + w * 16 + lr) * 2048 + kbB + lc * 8;

#define STAGE(bi, ti)                                                              \
  do {                                                                             \
    __builtin_amdgcn_global_load_lds(AS1(gk + (size_t)(ti) * (32 * 512)),          \
                                     AS3(&sm[bi][w * 512]), 16, 0, 0);             \
    __builtin_amdgcn_global_load_lds(AS1(gv + (size_t)(ti) * 32),                  \
                                     AS3(&sm[bi][(4 + w) * 512]), 16, 0, 0);       \
  } while (0)

#define MSK(pv, key)                                        \
  do {                                                      \
    if ((key) > q || (key) + 1024 < q) pv = -1.0e30f;       \
  } while (0)

  int kb = kbB;
  STAGE(0, 0);
  __syncthreads();
  for (int i = 0; i < nT; ++i, kb += 32) {
    if (i + 1 < nT) STAGE((i + 1) & 1, i + 1);
    if (kb >= myS && kb < myE) {  // wave-uniform
      const bf16_t* base = &sm[i & 1][(size_t)lane * 8];
      const bf16x8 k0 = *(const bf16x8*)(base);
      const bf16x8 k1 = *(const bf16x8*)(base + 512);
      const bf16x8 k2 = *(const bf16x8*)(base + 1024);
      const bf16x8 k3 = *(const bf16x8*)(base + 1536);
      const bf16x8 v0 = *(const bf16x8*)(base + 2048);
      const bf16x8 v1 = *(const bf16x8*)(base + 2560);
      const bf16x8 v2 = *(const bf16x8*)(base + 3072);
      const bf16x8 v3 = *(const bf16x8*)(base + 3584);
      floatx4 z0 = {}, z1 = {};
      z0 = __builtin_amdgcn_mfma_f32_16x16x32_bf16(k0, qf0, z0, 0, 0, 0);
      z0 = __builtin_amdgcn_mfma_f32_16x16x32_bf16(k1, qf1, z0, 0, 0, 0);
      z1 = __builtin_amdgcn_mfma_f32_16x16x32_bf16(k2, qf0, z1, 0, 0, 0);
      z1 = __builtin_amdgcn_mfma_f32_16x16x32_bf16(k3, qf1, z1, 0, 0, 0);
      float p0 = z0[0] * SC - 32.0f, p1 = z0[1] * SC - 32.0f;
      float p2 = z0[2] * SC - 32.0f, p3 = z0[3] * SC - 32.0f;
      float p4 = z1[0] * SC - 32.0f, p5 = z1[1] * SC - 32.0f;
      float p6 = z1[2] * SC - 32.0f, p7 = z1[3] * SC - 32.0f;
      if ((kb + 31 > qw) || (kb < qw - 1009)) {  // wave-uniform edge mask
        const int kq = kb + quad * 4;
        MSK(p0, kq + 0); MSK(p1, kq + 1); MSK(p2, kq + 2); MSK(p3, kq + 3);
        MSK(p4, kq + 16); MSK(p5, kq + 17); MSK(p6, kq + 18); MSK(p7, kq + 19);
      }
      bf16x8 pf;  // == P^T B-fragment directly (sigma-permuted V columns)
      pf[0] = (bf16_t)__builtin_amdgcn_exp2f(p0);
      pf[1] = (bf16_t)__builtin_amdgcn_exp2f(p1);
      pf[2] = (bf16_t)__builtin_amdgcn_exp2f(p2);
      pf[3] = (bf16_t)__builtin_amdgcn_exp2f(p3);
      pf[4] = (bf16_t)__builtin_amdgcn_exp2f(p4);
      pf[5] = (bf16_t)__builtin_amdgcn_exp2f(p5);
      pf[6] = (bf16_t)__builtin_amdgcn_exp2f(p6);
      pf[7] = (bf16_t)__builtin_amdgcn_exp2f(p7);
      accl = __builtin_amdgcn_mfma_f32_16x16x32_bf16(ones, pf, accl, 0, 0, 0);
      acc0 = __builtin_amdgcn_mfma_f32_16x16x32_bf16(v0, pf, acc0, 0, 0, 0);
      acc1 = __builtin_amdgcn_mfma_f32_16x16x32_bf16(v1, pf, acc1, 0, 0, 0);
      acc2 = __builtin_amdgcn_mfma_f32_16x16x32_bf16(v2, pf, acc2, 0, 0, 0);
      acc3 = __builtin_amdgcn_mfma_f32_16x16x32_bf16(v3, pf, acc3, 0, 0, 0);
    }
    __syncthreads();
  }
#undef STAGE
#undef MSK

  const float inv = 1.0f / accl[0];
  bf16_t* obase = ob_ + (size_t)q * 2048 + h * 64 + quad * 4;
  bf16x4 ov;
#pragma unroll
  for (int r = 0; r < 4; ++r) ov[r] = (bf16_t)(acc0[r] * inv);
  *(bf16x4*)(obase) = ov;
#pragma unroll
  for (int r = 0; r < 4; ++r) ov[r] = (bf16_t)(acc1[r] * inv);
  *(bf16x4*)(obase + 16) = ov;
#pragma unroll
  for (int r = 0; r < 4; ++r) ov[r] = (bf16_t)(acc2[r] * inv);
  *(bf16x4*)(obase + 32) = ov;
#pragma unroll
  for (int r = 0; r < 4; ++r) ov[r] = (bf16_t)(acc3[r] * inv);
  *(bf16x4*)(obase + 48) = ov;
}

extern "C" void kernel_launch(void* const* d_in, const int* in_sizes, int n_in, void* d_out,
                              int out_size, void* d_ws, size_t ws_size, hipStream_t stream) {
  (void)in_sizes;
  (void)n_in;
  (void)out_size;
  (void)ws_size;
  const float* x = (const float*)d_in[0];
  const float* wq = (const float*)d_in[1];
  const float* wk = (const float*)d_in[2];
  const float* wv = (const float*)d_in[3];
  const float* wo = (const float*)d_in[4];
  const float* fcos = (const float*)d_in[5];
  const float* fsin = (const float*)d_in[6];
  float* out = (float*)d_out;

  bf16_t* xb = (bf16_t*)d_ws;
  bf16_t* wt = xb + (size_t)2048 * 2048;
  bf16_t* qbuf = wt + (size_t)5120 * 2048;
  bf16_t* kbuf = qbuf + (size_t)2048 * 2048;
  bf16_t* vtb = kbuf + (size_t)2048 * 512;
  bf16_t* att = vtb + (size_t)512 * 2048;

  prep_k<<<4608, 256, 0, stream>>>(x, wq, wk, wv, wo, xb, wt);
  gemm_k<0><<<dim3(24, 64), 128, 0, stream>>>(xb, wt, qbuf, kbuf, vtb, nullptr, fcos, fsin);
  attn_k<<<dim3(32, 32), 256, 0, stream>>>(qbuf, kbuf, vtb, att);
  gemm_k<1><<<dim3(16, 64), 128, 0, stream>>>(att, wt + (size_t)3072 * 2048, nullptr, nullptr,
                                              nullptr, out, fcos, fsin);
}

// Round 10
// 209.689 us; speedup vs baseline: 1.3667x; 1.0610x over previous
//
#include <hip/hip_runtime.h>
#include <stdint.h>

typedef __bf16 bf16_t;
typedef __bf16 bf16x8 __attribute__((ext_vector_type(8)));
typedef __bf16 bf16x4 __attribute__((ext_vector_type(4)));
typedef float floatx4 __attribute__((ext_vector_type(4)));

#define AS3(p) ((__attribute__((address_space(3))) void*)(p))
#define AS1(p) ((__attribute__((address_space(1))) void*)(void*)(p))

// ---------- fused prep: cvt x (f32->bf16) + transpose-convert wq/wk/wv/wo ----------
__global__ __launch_bounds__(256) void prep_k(const float* __restrict__ x,
                                              const float* __restrict__ wq,
                                              const float* __restrict__ wk,
                                              const float* __restrict__ wv,
                                              const float* __restrict__ wo,
                                              bf16_t* __restrict__ xb,
                                              bf16_t* __restrict__ wt) {
  __shared__ __align__(16) bf16_t T[64][68];
  const int b = blockIdx.x;
  const int t = threadIdx.x;
  if (b < 2048) {
    const int i = (b * 256 + t) * 8;
    floatx4 a = *(const floatx4*)&x[i];
    floatx4 c = *(const floatx4*)&x[i + 4];
    bf16x8 o;
#pragma unroll
    for (int j = 0; j < 4; ++j) { o[j] = (bf16_t)a[j]; o[4 + j] = (bf16_t)c[j]; }
    *(bf16x8*)&xb[i] = o;
    return;
  }
  int b2 = b - 2048;
  const float* src;
  int ncols, bx, by;
  bf16_t* dst;
  if (b2 < 1024) {
    src = wq; ncols = 2048; dst = wt; bx = b2 & 31; by = b2 >> 5;
  } else if (b2 < 1280) {
    const int i2 = b2 - 1024;
    src = wk; ncols = 512; dst = wt + (size_t)2048 * 2048; bx = i2 & 7; by = i2 >> 3;
  } else if (b2 < 1536) {
    const int i2 = b2 - 1280;
    src = wv; ncols = 512; dst = wt + (size_t)2560 * 2048; bx = i2 & 7; by = i2 >> 3;
  } else {
    const int i2 = b2 - 1536;
    src = wo; ncols = 2048; dst = wt + (size_t)3072 * 2048; bx = i2 & 31; by = i2 >> 5;
  }
  const int nt = bx * 64, kt = by * 64;
  const int r0 = t >> 4;         // 0..15
  const int c0 = (t & 15) << 2;  // 0..60
#pragma unroll
  for (int p = 0; p < 4; ++p) {
    const int row = p * 16 + r0;
    floatx4 v = *(const floatx4*)&src[(size_t)(kt + row) * ncols + nt + c0];
    bf16x4 bb;
#pragma unroll
    for (int i = 0; i < 4; ++i) bb[i] = (bf16_t)v[i];
    *(bf16x4*)&T[row][c0] = bb;
  }
  __syncthreads();
#pragma unroll
  for (int p = 0; p < 4; ++p) {
    const int n = p * 16 + r0;
    bf16x4 tmp;
#pragma unroll
    for (int i = 0; i < 4; ++i) tmp[i] = T[c0 + i][n];
    *(bf16x4*)&dst[(size_t)(nt + n) * 2048 + kt + c0] = tmp;
  }
}

// ---------- GEMM: C[m][n] = sum_k A[m][k] * Bt[n][k], K=2048, A/Bt bf16 ----------
// R10: tile 64x64, 4 waves (wave tile 32x32, acc[2][2]), R0 schedule verbatim
// (single-buffered BK=64, plain __syncthreads — proven best across 6 variants).
// TLP is the only lever that ever moved gemm (R2: 12->6 waves/CU lost 1.5x);
// this raises it: gemm0 1536 blocks = 6/CU x 4 = 24 waves/CU, gemm1 1024 =
// 4/CU = 16 waves/CU (was 12/8). Cost: +33% L2 tile re-reads (headroom:
// 13.6 of 34.5 TB/s). LDS 16KB. Zero-conflict chunk-swizzle unchanged
// (stage row&7 = sr&7, read row&7 = l15&7). XCD-rectangle swizzle kept.
template <int EPI>
__global__ __launch_bounds__(256) void gemm_k(const bf16_t* __restrict__ A,
                                              const bf16_t* __restrict__ Bt,
                                              bf16_t* __restrict__ o0,
                                              bf16_t* __restrict__ o1,
                                              bf16_t* __restrict__ o2,
                                              float* __restrict__ fo,
                                              const float* __restrict__ fcos,
                                              const float* __restrict__ fsin) {
  constexpr int K = 2048;
  __shared__ __align__(16) bf16_t As[64 * 64];
  __shared__ __align__(16) bf16_t Bs[64 * 64];
  const int tid = threadIdx.x;
  const int lane = tid & 63;
  const int w = tid >> 6;   // 0..3
  const int wr = w >> 1;    // M-half
  const int wc = w & 1;     // N-half
  const int quad = lane >> 4;
  const int l15 = lane & 15;

  // XCD-rectangle swizzle: nwg % 8 == 0; 8 XCDs tiled 2(x) x 4(y).
  const int nx = gridDim.x, ny = gridDim.y;
  const int flat = blockIdx.y * nx + blockIdx.x;
  const int xcd = flat & 7;
  const int c = flat >> 3;  // within-XCD order
  const int CW = nx >> 1, CH = ny >> 2;
  const int bx = (xcd & 1) * CW + (c % CW);
  const int by = (xcd >> 1) * CH + (c / CW);
  const int m0 = by * 64;
  const int n0 = bx * 64;

  // staging: lane covers row (base + lane>>3), swizzled chunk (lane&7)^(row&7)
  const int sr = lane >> 3;
  const int sc = ((lane & 7) ^ (sr & 7)) << 3;
  const bf16_t* gA = A + (size_t)(m0 + w * 16 + sr) * K + sc;   // 2 instrs/wave
  const bf16_t* gB = Bt + (size_t)(n0 + w * 16 + sr) * K + sc;  // 2 instrs/wave
  bf16_t* lA = &As[w * 1024];
  bf16_t* lB = &Bs[w * 1024];
  floatx4 acc[2][2] = {};

  for (int k0 = 0; k0 < K; k0 += 64) {
    __builtin_amdgcn_global_load_lds(AS1(gA + k0), AS3(lA), 16, 0, 0);
    __builtin_amdgcn_global_load_lds(AS1(gA + 8 * K + k0), AS3(lA + 512), 16, 0, 0);
    __builtin_amdgcn_global_load_lds(AS1(gB + k0), AS3(lB), 16, 0, 0);
    __builtin_amdgcn_global_load_lds(AS1(gB + 8 * K + k0), AS3(lB + 512), 16, 0, 0);
    __syncthreads();
#pragma unroll
    for (int kk = 0; kk < 2; ++kk) {
      const int co = ((kk * 4 + quad) ^ (l15 & 7)) << 3;  // per-lane const offset
      bf16x8 af[2], bfr[2];
#pragma unroll
      for (int i = 0; i < 2; ++i)
        af[i] = *(const bf16x8*)&As[(wr * 32 + i * 16 + l15) * 64 + co];
#pragma unroll
      for (int i = 0; i < 2; ++i)
        bfr[i] = *(const bf16x8*)&Bs[(wc * 32 + i * 16 + l15) * 64 + co];
#pragma unroll
      for (int mi = 0; mi < 2; ++mi)
#pragma unroll
        for (int ni = 0; ni < 2; ++ni)
          acc[mi][ni] =
              __builtin_amdgcn_mfma_f32_16x16x32_bf16(af[mi], bfr[ni], acc[mi][ni], 0, 0, 0);
    }
    __syncthreads();
  }

  if constexpr (EPI == 0) {
#pragma unroll
    for (int ni = 0; ni < 2; ++ni) {
      const int col = n0 + wc * 32 + ni * 16 + l15;
#pragma unroll
      for (int mi = 0; mi < 2; ++mi) {
        const int sb = m0 + wr * 32 + mi * 16 + quad * 4;
        if (col < 2560) {  // uniform per wave (boundaries are multiples of 16)
          const int fi = (col & 63) >> 1;
#pragma unroll
          for (int r = 0; r < 4; ++r) {
            const float v = acc[mi][ni][r];
            const float prt = __shfl_xor(v, 1);  // partner column within rope pair
            const int s = sb + r;
            const float cc = fcos[s * 32 + fi];
            const float sn = fsin[s * 32 + fi];
            const float ov = (col & 1) ? (prt * sn + v * cc) : (v * cc - prt * sn);
            if (col < 2048)
              o0[(size_t)s * 2048 + col] = (bf16_t)ov;
            else
              o1[(size_t)s * 512 + (col - 2048)] = (bf16_t)ov;
          }
        } else {
          // sigma permutation within the 32-aligned s-block (m0+wr*32 is
          // 32-aligned; mi in {0,1} spans it): storage quad*8 + mi*4 + r
          const int sp = (m0 + wr * 32) | (quad * 8 + mi * 4);
          bf16x4 pv;
#pragma unroll
          for (int r = 0; r < 4; ++r) pv[r] = (bf16_t)acc[mi][ni][r];
          *(bf16x4*)&o2[(size_t)(col - 2560) * 2048 + sp] = pv;
        }
      }
    }
  } else {
#pragma unroll
    for (int ni = 0; ni < 2; ++ni) {
      const int col = n0 + wc * 32 + ni * 16 + l15;
#pragma unroll
      for (int mi = 0; mi < 2; ++mi) {
        const int sb = m0 + wr * 32 + mi * 16 + quad * 4;
#pragma unroll
        for (int r = 0; r < 4; ++r) fo[(size_t)(sb + r) * 2048 + col] = acc[mi][ni][r];
      }
    }
  }
}

// ---------- flash attention, S^T formulation, LDS-staged K/V (R0, proven) ----------
__global__ __launch_bounds__(256) void attn_k(const bf16_t* __restrict__ qb_,
                                              const bf16_t* __restrict__ kb_,
                                              const bf16_t* __restrict__ vt_,
                                              bf16_t* __restrict__ ob_) {
  __shared__ __align__(16) bf16_t sm[2][8 * 512];
  const int lane = threadIdx.x & 63, w = threadIdx.x >> 6;
  const int quad = lane >> 4, l15 = lane & 15;
  const int h = blockIdx.y, g = h >> 2;
  const int qb = (gridDim.x - 1 - blockIdx.x) * 64;  // heavy blocks first
  const int qw = qb + w * 16;
  const int q = qw + l15;
  const bf16_t* qrow = qb_ + (size_t)q * 2048 + h * 64;
  const bf16x8 qf0 = *(const bf16x8*)(qrow + quad * 8);
  const bf16x8 qf1 = *(const bf16x8*)(qrow + 32 + quad * 8);
  floatx4 acc0 = {}, acc1 = {}, acc2 = {}, acc3 = {}, accl = {};
  const float SC = 0.125f * 1.44269504088896340736f;  // scale * log2(e)
  bf16x8 ones;
#pragma unroll
  for (int i = 0; i < 8; ++i) ones[i] = (bf16_t)1.0f;

  int kbB = qb - 1024;
  if (kbB < 0) kbB = 0;
  kbB &= ~31;
  const int nT = (qb + 64 - kbB) >> 5;  // block-level tile count
  int myS = qw - 1024;
  if (myS < 0) myS = 0;
  myS &= ~31;
  const int myE = qw + 16;

  const int lr = lane & 15, lc = lane >> 4;
  const bf16_t* gk = kb_ + (size_t)(kbB + (w >> 1) * 16 + lr) * 512 + g * 64 +
                     ((w & 1) * 4 + lc) * 8;
  const bf16_t* gv = vt_ + (size_t)(g * 64 + w * 16 + lr) * 2048 + kbB + lc * 8;

#define STAGE(bi, ti)                                                              \
  do {                                                                             \
    __builtin_amdgcn_global_load_lds(AS1(gk + (size_t)(ti) * (32 * 512)),          \
                                     AS3(&sm[bi][w * 512]), 16, 0, 0);             \
    __builtin_amdgcn_global_load_lds(AS1(gv + (size_t)(ti) * 32),                  \
                                     AS3(&sm[bi][(4 + w) * 512]), 16, 0, 0);       \
  } while (0)

#define MSK(pv, key)                                        \
  do {                                                      \
    if ((key) > q || (key) + 1024 < q) pv = -1.0e30f;       \
  } while (0)

  int kb = kbB;
  STAGE(0, 0);
  __syncthreads();
  for (int i = 0; i < nT; ++i, kb += 32) {
    if (i + 1 < nT) STAGE((i + 1) & 1, i + 1);
    if (kb >= myS && kb < myE) {  // wave-uniform
      const bf16_t* base = &sm[i & 1][(size_t)lane * 8];
      const bf16x8 k0 = *(const bf16x8*)(base);
      const bf16x8 k1 = *(const bf16x8*)(base + 512);
      const bf16x8 k2 = *(const bf16x8*)(base + 1024);
      const bf16x8 k3 = *(const bf16x8*)(base + 1536);
      const bf16x8 v0 = *(const bf16x8*)(base + 2048);
      const bf16x8 v1 = *(const bf16x8*)(base + 2560);
      const bf16x8 v2 = *(const bf16x8*)(base + 3072);
      const bf16x8 v3 = *(const bf16x8*)(base + 3584);
      floatx4 z0 = {}, z1 = {};
      z0 = __builtin_amdgcn_mfma_f32_16x16x32_bf16(k0, qf0, z0, 0, 0, 0);
      z0 = __builtin_amdgcn_mfma_f32_16x16x32_bf16(k1, qf1, z0, 0, 0, 0);
      z1 = __builtin_amdgcn_mfma_f32_16x16x32_bf16(k2, qf0, z1, 0, 0, 0);
      z1 = __builtin_amdgcn_mfma_f32_16x16x32_bf16(k3, qf1, z1, 0, 0, 0);
      float p0 = z0[0] * SC - 32.0f, p1 = z0[1] * SC - 32.0f;
      float p2 = z0[2] * SC - 32.0f, p3 = z0[3] * SC - 32.0f;
      float p4 = z1[0] * SC - 32.0f, p5 = z1[1] * SC - 32.0f;
      float p6 = z1[2] * SC - 32.0f, p7 = z1[3] * SC - 32.0f;
      if ((kb + 31 > qw) || (kb < qw - 1009)) {  // wave-uniform edge mask
        const int kq = kb + quad * 4;
        MSK(p0, kq + 0); MSK(p1, kq + 1); MSK(p2, kq + 2); MSK(p3, kq + 3);
        MSK(p4, kq + 16); MSK(p5, kq + 17); MSK(p6, kq + 18); MSK(p7, kq + 19);
      }
      bf16x8 pf;  // == P^T B-fragment directly (sigma-permuted V columns)
      pf[0] = (bf16_t)__builtin_amdgcn_exp2f(p0);
      pf[1] = (bf16_t)__builtin_amdgcn_exp2f(p1);
      pf[2] = (bf16_t)__builtin_amdgcn_exp2f(p2);
      pf[3] = (bf16_t)__builtin_amdgcn_exp2f(p3);
      pf[4] = (bf16_t)__builtin_amdgcn_exp2f(p4);
      pf[5] = (bf16_t)__builtin_amdgcn_exp2f(p5);
      pf[6] = (bf16_t)__builtin_amdgcn_exp2f(p6);
      pf[7] = (bf16_t)__builtin_amdgcn_exp2f(p7);
      accl = __builtin_amdgcn_mfma_f32_16x16x32_bf16(ones, pf, accl, 0, 0, 0);
      acc0 = __builtin_amdgcn_mfma_f32_16x16x32_bf16(v0, pf, acc0, 0, 0, 0);
      acc1 = __builtin_amdgcn_mfma_f32_16x16x32_bf16(v1, pf, acc1, 0, 0, 0);
      acc2 = __builtin_amdgcn_mfma_f32_16x16x32_bf16(v2, pf, acc2, 0, 0, 0);
      acc3 = __builtin_amdgcn_mfma_f32_16x16x32_bf16(v3, pf, acc3, 0, 0, 0);
    }
    __syncthreads();
  }
#undef STAGE
#undef MSK

  const float inv = 1.0f / accl[0];
  bf16_t* obase = ob_ + (size_t)q * 2048 + h * 64 + quad * 4;
  bf16x4 ov;
#pragma unroll
  for (int r = 0; r < 4; ++r) ov[r] = (bf16_t)(acc0[r] * inv);
  *(bf16x4*)(obase) = ov;
#pragma unroll
  for (int r = 0; r < 4; ++r) ov[r] = (bf16_t)(acc1[r] * inv);
  *(bf16x4*)(obase + 16) = ov;
#pragma unroll
  for (int r = 0; r < 4; ++r) ov[r] = (bf16_t)(acc2[r] * inv);
  *(bf16x4*)(obase + 32) = ov;
#pragma unroll
  for (int r = 0; r < 4; ++r) ov[r] = (bf16_t)(acc3[r] * inv);
  *(bf16x4*)(obase + 48) = ov;
}

extern "C" void kernel_launch(void* const* d_in, const int* in_sizes, int n_in, void* d_out,
                              int out_size, void* d_ws, size_t ws_size, hipStream_t stream) {
  (void)in_sizes;
  (void)n_in;
  (void)out_size;
  (void)ws_size;
  const float* x = (const float*)d_in[0];
  const float* wq = (const float*)d_in[1];
  const float* wk = (const float*)d_in[2];
  const float* wv = (const float*)d_in[3];
  const float* wo = (const float*)d_in[4];
  const float* fcos = (const float*)d_in[5];
  const float* fsin = (const float*)d_in[6];
  float* out = (float*)d_out;

  bf16_t* xb = (bf16_t*)d_ws;
  bf16_t* wt = xb + (size_t)2048 * 2048;
  bf16_t* qbuf = wt + (size_t)5120 * 2048;
  bf16_t* kbuf = qbuf + (size_t)2048 * 2048;
  bf16_t* vtb = kbuf + (size_t)2048 * 512;
  bf16_t* att = vtb + (size_t)512 * 2048;

  prep_k<<<4608, 256, 0, stream>>>(x, wq, wk, wv, wo, xb, wt);
  gemm_k<0><<<dim3(48, 32), 256, 0, stream>>>(xb, wt, qbuf, kbuf, vtb, nullptr, fcos, fsin);
  attn_k<<<dim3(32, 32), 256, 0, stream>>>(qbuf, kbuf, vtb, att);
  gemm_k<1><<<dim3(32, 32), 256, 0, stream>>>(att, wt + (size_t)3072 * 2048, nullptr, nullptr,
                                              nullptr, out, fcos, fsin);
}

// Round 11
// 193.818 us; speedup vs baseline: 1.4786x; 1.0819x over previous
//
#include <hip/hip_runtime.h>
#include <stdint.h>

typedef __bf16 bf16_t;
typedef __bf16 bf16x8 __attribute__((ext_vector_type(8)));
typedef __bf16 bf16x4 __attribute__((ext_vector_type(4)));
typedef float floatx4 __attribute__((ext_vector_type(4)));

#define AS3(p) ((__attribute__((address_space(3))) void*)(p))
#define AS1(p) ((__attribute__((address_space(1))) void*)(void*)(p))

// ---------- fused prep: cvt x (f32->bf16) + transpose-convert wq/wk/wv/wo ----------
__global__ __launch_bounds__(256) void prep_k(const float* __restrict__ x,
                                              const float* __restrict__ wq,
                                              const float* __restrict__ wk,
                                              const float* __restrict__ wv,
                                              const float* __restrict__ wo,
                                              bf16_t* __restrict__ xb,
                                              bf16_t* __restrict__ wt) {
  __shared__ __align__(16) bf16_t T[64][68];
  const int b = blockIdx.x;
  const int t = threadIdx.x;
  if (b < 2048) {
    const int i = (b * 256 + t) * 8;
    floatx4 a = *(const floatx4*)&x[i];
    floatx4 c = *(const floatx4*)&x[i + 4];
    bf16x8 o;
#pragma unroll
    for (int j = 0; j < 4; ++j) { o[j] = (bf16_t)a[j]; o[4 + j] = (bf16_t)c[j]; }
    *(bf16x8*)&xb[i] = o;
    return;
  }
  int b2 = b - 2048;
  const float* src;
  int ncols, bx, by;
  bf16_t* dst;
  if (b2 < 1024) {
    src = wq; ncols = 2048; dst = wt; bx = b2 & 31; by = b2 >> 5;
  } else if (b2 < 1280) {
    const int i2 = b2 - 1024;
    src = wk; ncols = 512; dst = wt + (size_t)2048 * 2048; bx = i2 & 7; by = i2 >> 3;
  } else if (b2 < 1536) {
    const int i2 = b2 - 1280;
    src = wv; ncols = 512; dst = wt + (size_t)2560 * 2048; bx = i2 & 7; by = i2 >> 3;
  } else {
    const int i2 = b2 - 1536;
    src = wo; ncols = 2048; dst = wt + (size_t)3072 * 2048; bx = i2 & 31; by = i2 >> 5;
  }
  const int nt = bx * 64, kt = by * 64;
  const int r0 = t >> 4;         // 0..15
  const int c0 = (t & 15) << 2;  // 0..60
#pragma unroll
  for (int p = 0; p < 4; ++p) {
    const int row = p * 16 + r0;
    floatx4 v = *(const floatx4*)&src[(size_t)(kt + row) * ncols + nt + c0];
    bf16x4 bb;
#pragma unroll
    for (int i = 0; i < 4; ++i) bb[i] = (bf16_t)v[i];
    *(bf16x4*)&T[row][c0] = bb;
  }
  __syncthreads();
#pragma unroll
  for (int p = 0; p < 4; ++p) {
    const int n = p * 16 + r0;
    bf16x4 tmp;
#pragma unroll
    for (int i = 0; i < 4; ++i) tmp[i] = T[c0 + i][n];
    *(bf16x4*)&dst[(size_t)(nt + n) * 2048 + kt + c0] = tmp;
  }
}

// ---------- GEMM: C[m][n] = sum_k A[m][k] * Bt[n][k], K=2048, A/Bt bf16 ----------
// LOCKED (R11): exact R0 structure — 64x128 tile, 4 waves, acc[4][2], BK=64,
// single-buffered, plain __syncthreads, zero-conflict chunk-swizzle — plus
// XCD-rectangle swizzle (FETCH -20%, validated). Falsified alternatives:
// compiler-dbuf (R1), 2-wave same-grid (R2), BK=128 (R5), counted-vmcnt (R6),
// B-to-reg (R7), 32x128 2-wave (R9), 64x64 24-waves/CU (R10). 12 waves/CU at
// this tile is the measured optimum of the structure family (~591 TF gemm0).
template <int EPI>
__global__ __launch_bounds__(256) void gemm_k(const bf16_t* __restrict__ A,
                                              const bf16_t* __restrict__ Bt,
                                              bf16_t* __restrict__ o0,
                                              bf16_t* __restrict__ o1,
                                              bf16_t* __restrict__ o2,
                                              float* __restrict__ fo,
                                              const float* __restrict__ fcos,
                                              const float* __restrict__ fsin) {
  constexpr int K = 2048;
  __shared__ __align__(16) bf16_t As[64 * 64];
  __shared__ __align__(16) bf16_t Bs[128 * 64];
  const int tid = threadIdx.x;
  const int lane = tid & 63;
  const int w = tid >> 6;
  const int quad = lane >> 4;
  const int l15 = lane & 15;

  // XCD-rectangle swizzle: nwg % 8 == 0; 8 XCDs tiled 2(x) x 4(y).
  const int nx = gridDim.x, ny = gridDim.y;
  const int flat = blockIdx.y * nx + blockIdx.x;
  const int xcd = flat & 7;
  const int c = flat >> 3;  // within-XCD order
  const int CW = nx >> 1, CH = ny >> 2;
  const int bx = (xcd & 1) * CW + (c % CW);
  const int by = (xcd >> 1) * CH + (c / CW);
  const int m0 = by * 64;
  const int n0 = bx * 128;

  // staging: lane covers row (base + lane>>3), swizzled chunk (lane&7)^(row&7)
  const int sr = lane >> 3;
  const int sc = ((lane & 7) ^ (sr & 7)) << 3;
  const bf16_t* gA = A + (size_t)(m0 + w * 16 + sr) * K + sc;   // A instrs j=2w,2w+1
  const bf16_t* gB = Bt + (size_t)(n0 + w * 32 + sr) * K + sc;  // B instrs j=4w..4w+3
  bf16_t* lA = &As[w * 1024];
  bf16_t* lB = &Bs[w * 2048];
  floatx4 acc[4][2] = {};

  for (int k0 = 0; k0 < K; k0 += 64) {
    __builtin_amdgcn_global_load_lds(AS1(gA + k0), AS3(lA), 16, 0, 0);
    __builtin_amdgcn_global_load_lds(AS1(gA + 8 * K + k0), AS3(lA + 512), 16, 0, 0);
#pragma unroll
    for (int qq = 0; qq < 4; ++qq)
      __builtin_amdgcn_global_load_lds(AS1(gB + (size_t)qq * 8 * K + k0),
                                       AS3(lB + qq * 512), 16, 0, 0);
    __syncthreads();
#pragma unroll
    for (int kk = 0; kk < 2; ++kk) {
      const int co = ((kk * 4 + quad) ^ (l15 & 7)) << 3;  // per-lane const offset
      bf16x8 af[4], bfr[2];
#pragma unroll
      for (int i = 0; i < 4; ++i) af[i] = *(const bf16x8*)&As[(i * 16 + l15) * 64 + co];
#pragma unroll
      for (int i = 0; i < 2; ++i)
        bfr[i] = *(const bf16x8*)&Bs[(w * 32 + i * 16 + l15) * 64 + co];
#pragma unroll
      for (int mi = 0; mi < 4; ++mi)
#pragma unroll
        for (int ni = 0; ni < 2; ++ni)
          acc[mi][ni] =
              __builtin_amdgcn_mfma_f32_16x16x32_bf16(af[mi], bfr[ni], acc[mi][ni], 0, 0, 0);
    }
    __syncthreads();
  }

  if constexpr (EPI == 0) {
#pragma unroll
    for (int ni = 0; ni < 2; ++ni) {
      const int col = n0 + w * 32 + ni * 16 + l15;
#pragma unroll
      for (int mi = 0; mi < 4; ++mi) {
        const int sb = m0 + mi * 16 + quad * 4;
        if (col < 2560) {  // uniform per wave (boundaries are multiples of 16)
          const int fi = (col & 63) >> 1;
#pragma unroll
          for (int r = 0; r < 4; ++r) {
            const float v = acc[mi][ni][r];
            const float prt = __shfl_xor(v, 1);  // partner column within rope pair
            const int s = sb + r;
            const float cc = fcos[s * 32 + fi];
            const float sn = fsin[s * 32 + fi];
            const float ov = (col & 1) ? (prt * sn + v * cc) : (v * cc - prt * sn);
            if (col < 2048)
              o0[(size_t)s * 2048 + col] = (bf16_t)ov;
            else
              o1[(size_t)s * 512 + (col - 2048)] = (bf16_t)ov;
          }
        } else {
          // sigma permutation within the 32-aligned s-block:
          // logical (t=mi&1, qs=quad, r) -> storage quad*8 + (mi&1)*4 + r
          const int sp = (sb & ~31) | (quad * 8 + (mi & 1) * 4);
          bf16x4 pv;
#pragma unroll
          for (int r = 0; r < 4; ++r) pv[r] = (bf16_t)acc[mi][ni][r];
          *(bf16x4*)&o2[(size_t)(col - 2560) * 2048 + sp] = pv;
        }
      }
    }
  } else {
#pragma unroll
    for (int ni = 0; ni < 2; ++ni) {
      const int col = n0 + w * 32 + ni * 16 + l15;
#pragma unroll
      for (int mi = 0; mi < 4; ++mi) {
        const int sb = m0 + mi * 16 + quad * 4;
#pragma unroll
        for (int r = 0; r < 4; ++r) fo[(size_t)(sb + r) * 2048 + col] = acc[mi][ni][r];
      }
    }
  }
}

// ---------- flash attention, S^T formulation, LDS-staged K/V ----------
// R11: 8 waves / 128 q-rows per block (was 4/64). Same proven inner loop and
// LDS layout; each of 8 waves issues ONE global_load_lds (waves 0-3 stage the
// K tile, 4-7 the V tile) into the same slot arrangement. Halves L2->LDS
// staging traffic per q-row (8KB/tile now serves 128 rows) at identical TLP
// (512 blocks = 2/CU x 8 = 16 waves/CU). R8 proved staging is load-bearing
// (de-stage: 3x regression); this keeps it but halves its cost.
__global__ __launch_bounds__(512) void attn_k(const bf16_t* __restrict__ qb_,
                                              const bf16_t* __restrict__ kb_,
                                              const bf16_t* __restrict__ vt_,
                                              bf16_t* __restrict__ ob_) {
  __shared__ __align__(16) bf16_t sm[2][8 * 512];
  const int lane = threadIdx.x & 63, w = threadIdx.x >> 6;  // w 0..7
  const int quad = lane >> 4, l15 = lane & 15;
  const int h = blockIdx.y, g = h >> 2;
  const int qb = (gridDim.x - 1 - blockIdx.x) * 128;  // heavy blocks first
  const int qw = qb + w * 16;
  const int q = qw + l15;
  const bf16_t* qrow = qb_ + (size_t)q * 2048 + h * 64;
  const bf16x8 qf0 = *(const bf16x8*)(qrow + quad * 8);
  const bf16x8 qf1 = *(const bf16x8*)(qrow + 32 + quad * 8);
  floatx4 acc0 = {}, acc1 = {}, acc2 = {}, acc3 = {}, accl = {};
  const float SC = 0.125f * 1.44269504088896340736f;  // scale * log2(e)
  bf16x8 ones;
#pragma unroll
  for (int i = 0; i < 8; ++i) ones[i] = (bf16_t)1.0f;

  int kbB = qb - 1024;
  if (kbB < 0) kbB = 0;
  kbB &= ~31;
  const int nT = (qb + 128 - kbB) >> 5;  // block-level tile count
  int myS = qw - 1024;
  if (myS < 0) myS = 0;
  myS &= ~31;
  const int myE = qw + 16;

  const int lr = lane & 15, lc = lane >> 4;
  // waves 0-3 stage the K tile (rows kb..kb+31, cols g*64..+63);
  // waves 4-7 stage the V^T tile (rows g*64..+63, cols kb..kb+31).
  const bf16_t* gst =
      (w < 4) ? kb_ + (size_t)(kbB + (w >> 1) * 16 + lr) * 512 + g * 64 +
                    ((w & 1) * 4 + lc) * 8
              : vt_ + (size_t)(g * 64 + (w - 4) * 16 + lr) * 2048 + kbB + lc * 8;
  const size_t tstep = (w < 4) ? (size_t)32 * 512 : (size_t)32;

#define STAGE(bi, ti)                                                              \
  __builtin_amdgcn_global_load_lds(AS1(gst + (size_t)(ti) * tstep),                \
                                   AS3(&sm[bi][w * 512]), 16, 0, 0)

#define MSK(pv, key)                                        \
  do {                                                      \
    if ((key) > q || (key) + 1024 < q) pv = -1.0e30f;       \
  } while (0)

  int kb = kbB;
  STAGE(0, 0);
  __syncthreads();
  for (int i = 0; i < nT; ++i, kb += 32) {
    if (i + 1 < nT) STAGE((i + 1) & 1, i + 1);
    if (kb >= myS && kb < myE) {  // wave-uniform
      const bf16_t* base = &sm[i & 1][(size_t)lane * 8];
      const bf16x8 k0 = *(const bf16x8*)(base);
      const bf16x8 k1 = *(const bf16x8*)(base + 512);
      const bf16x8 k2 = *(const bf16x8*)(base + 1024);
      const bf16x8 k3 = *(const bf16x8*)(base + 1536);
      const bf16x8 v0 = *(const bf16x8*)(base + 2048);
      const bf16x8 v1 = *(const bf16x8*)(base + 2560);
      const bf16x8 v2 = *(const bf16x8*)(base + 3072);
      const bf16x8 v3 = *(const bf16x8*)(base + 3584);
      floatx4 z0 = {}, z1 = {};
      z0 = __builtin_amdgcn_mfma_f32_16x16x32_bf16(k0, qf0, z0, 0, 0, 0);
      z0 = __builtin_amdgcn_mfma_f32_16x16x32_bf16(k1, qf1, z0, 0, 0, 0);
      z1 = __builtin_amdgcn_mfma_f32_16x16x32_bf16(k2, qf0, z1, 0, 0, 0);
      z1 = __builtin_amdgcn_mfma_f32_16x16x32_bf16(k3, qf1, z1, 0, 0, 0);
      float p0 = z0[0] * SC - 32.0f, p1 = z0[1] * SC - 32.0f;
      float p2 = z0[2] * SC - 32.0f, p3 = z0[3] * SC - 32.0f;
      float p4 = z1[0] * SC - 32.0f, p5 = z1[1] * SC - 32.0f;
      float p6 = z1[2] * SC - 32.0f, p7 = z1[3] * SC - 32.0f;
      if ((kb + 31 > qw) || (kb < qw - 1009)) {  // wave-uniform edge mask
        const int kq = kb + quad * 4;
        MSK(p0, kq + 0); MSK(p1, kq + 1); MSK(p2, kq + 2); MSK(p3, kq + 3);
        MSK(p4, kq + 16); MSK(p5, kq + 17); MSK(p6, kq + 18); MSK(p7, kq + 19);
      }
      bf16x8 pf;  // == P^T B-fragment directly (sigma-permuted V columns)
      pf[0] = (bf16_t)__builtin_amdgcn_exp2f(p0);
      pf[1] = (bf16_t)__builtin_amdgcn_exp2f(p1);
      pf[2] = (bf16_t)__builtin_amdgcn_exp2f(p2);
      pf[3] = (bf16_t)__builtin_amdgcn_exp2f(p3);
      pf[4] = (bf16_t)__builtin_amdgcn_exp2f(p4);
      pf[5] = (bf16_t)__builtin_amdgcn_exp2f(p5);
      pf[6] = (bf16_t)__builtin_amdgcn_exp2f(p6);
      pf[7] = (bf16_t)__builtin_amdgcn_exp2f(p7);
      accl = __builtin_amdgcn_mfma_f32_16x16x32_bf16(ones, pf, accl, 0, 0, 0);
      acc0 = __builtin_amdgcn_mfma_f32_16x16x32_bf16(v0, pf, acc0, 0, 0, 0);
      acc1 = __builtin_amdgcn_mfma_f32_16x16x32_bf16(v1, pf, acc1, 0, 0, 0);
      acc2 = __builtin_amdgcn_mfma_f32_16x16x32_bf16(v2, pf, acc2, 0, 0, 0);
      acc3 = __builtin_amdgcn_mfma_f32_16x16x32_bf16(v3, pf, acc3, 0, 0, 0);
    }
    __syncthreads();
  }
#undef STAGE
#undef MSK

  const float inv = 1.0f / accl[0];
  bf16_t* obase = ob_ + (size_t)q * 2048 + h * 64 + quad * 4;
  bf16x4 ov;
#pragma unroll
  for (int r = 0; r < 4; ++r) ov[r] = (bf16_t)(acc0[r] * inv);
  *(bf16x4*)(obase) = ov;
#pragma unroll
  for (int r = 0; r < 4; ++r) ov[r] = (bf16_t)(acc1[r] * inv);
  *(bf16x4*)(obase + 16) = ov;
#pragma unroll
  for (int r = 0; r < 4; ++r) ov[r] = (bf16_t)(acc2[r] * inv);
  *(bf16x4*)(obase + 32) = ov;
#pragma unroll
  for (int r = 0; r < 4; ++r) ov[r] = (bf16_t)(acc3[r] * inv);
  *(bf16x4*)(obase + 48) = ov;
}

extern "C" void kernel_launch(void* const* d_in, const int* in_sizes, int n_in, void* d_out,
                              int out_size, void* d_ws, size_t ws_size, hipStream_t stream) {
  (void)in_sizes;
  (void)n_in;
  (void)out_size;
  (void)ws_size;
  const float* x = (const float*)d_in[0];
  const float* wq = (const float*)d_in[1];
  const float* wk = (const float*)d_in[2];
  const float* wv = (const float*)d_in[3];
  const float* wo = (const float*)d_in[4];
  const float* fcos = (const float*)d_in[5];
  const float* fsin = (const float*)d_in[6];
  float* out = (float*)d_out;

  bf16_t* xb = (bf16_t*)d_ws;
  bf16_t* wt = xb + (size_t)2048 * 2048;
  bf16_t* qbuf = wt + (size_t)5120 * 2048;
  bf16_t* kbuf = qbuf + (size_t)2048 * 2048;
  bf16_t* vtb = kbuf + (size_t)2048 * 512;
  bf16_t* att = vtb + (size_t)512 * 2048;

  prep_k<<<4608, 256, 0, stream>>>(x, wq, wk, wv, wo, xb, wt);
  gemm_k<0><<<dim3(24, 32), 256, 0, stream>>>(xb, wt, qbuf, kbuf, vtb, nullptr, fcos, fsin);
  attn_k<<<dim3(16, 32), 512, 0, stream>>>(qbuf, kbuf, vtb, att);
  gemm_k<1><<<dim3(16, 32), 256, 0, stream>>>(att, wt + (size_t)3072 * 2048, nullptr, nullptr,
                                              nullptr, out, fcos, fsin);
}